// Round 9
// baseline (490.931 us; speedup 1.0000x reference)
//
#include <hip/hip_runtime.h>

#define NN 50000   // nodes
#define NE 10000   // hyperedges
#define NI 800000  // incidences
#define CH 128     // channels
#define EPSV 1e-5f
#define ESTR 160   // ELL stride per edge  (deg ~ 80 +- 8.9; 160 = +9 sd)
#define NSTR 64    // ELL stride per node  (deg ~ 16 +- 4;  64 = +12 sd)

// ---------------------------------------------------------------------------
// one-pass ELL build (u16 payload): cursor atomics give slot + degree count
__global__ __launch_bounds__(256) void k_fill_ell(const int* __restrict__ nidx,
    const int* __restrict__ eidx, int* __restrict__ cnt_e,
    int* __restrict__ cnt_n, unsigned short* __restrict__ ell_e,
    unsigned short* __restrict__ ell_n) {
  int i = blockIdx.x * 256 + threadIdx.x;
  if (i >= NI) return;
  int n = nidx[i], e = eidx[i];
  int ce = atomicAdd(&cnt_e[e], 1);
  if (ce < ESTR) ell_e[(long)e * ESTR + ce] = (unsigned short)n;
  int cn = atomicAdd(&cnt_n[n], 1);
  if (cn < NSTR) ell_n[(long)n * NSTR + cn] = (unsigned short)e;
}

// ---------------------------------------------------------------------------
// fused edge-mean gather + GEMM:
//   As[r][:] = (scale,shift applied) mean_{n in edge e0+r} X[n]   (LDS)
//   Eout[e][o] = sum_k As[e-e0][k] * W[o][k]
__global__ __launch_bounds__(256) void k_edge_gemm(const int* __restrict__ cnt_e,
    const unsigned short* __restrict__ ell_e, const float* __restrict__ X,
    const float* __restrict__ W, float* __restrict__ Eout,
    const float* __restrict__ scale, const float* __restrict__ shift) {
  __shared__ float As[32][132];
  const int tid = threadIdx.x;
  const int e0 = blockIdx.x * 32;
  const int lane = tid & 31, grp = tid >> 5;
  const int c = lane * 4;

  // ---- gather 32 edge means into As (8 edges in parallel, 4 rounds) ----
  for (int it = 0; it < 4; ++it) {
    int r = it * 8 + grp;
    int e = e0 + r;
    int t = 0;
    if (e < NE) { t = cnt_e[e]; if (t > ESTR) t = ESTR; }
    const unsigned short* base = ell_e + (long)e * ESTR;
    float4 acc = make_float4(0.f, 0.f, 0.f, 0.f);
    int j = 0;
    for (; j + 4 <= t; j += 4) {
      ushort4 nn = *reinterpret_cast<const ushort4*>(base + j);
      float4 v0 = *reinterpret_cast<const float4*>(&X[(long)nn.x * CH + c]);
      float4 v1 = *reinterpret_cast<const float4*>(&X[(long)nn.y * CH + c]);
      float4 v2 = *reinterpret_cast<const float4*>(&X[(long)nn.z * CH + c]);
      float4 v3 = *reinterpret_cast<const float4*>(&X[(long)nn.w * CH + c]);
      acc.x += (v0.x + v1.x) + (v2.x + v3.x);
      acc.y += (v0.y + v1.y) + (v2.y + v3.y);
      acc.z += (v0.z + v1.z) + (v2.z + v3.z);
      acc.w += (v0.w + v1.w) + (v2.w + v3.w);
    }
    for (; j < t; ++j) {
      int n = base[j];
      float4 v = *reinterpret_cast<const float4*>(&X[(long)n * CH + c]);
      acc.x += v.x; acc.y += v.y; acc.z += v.z; acc.w += v.w;
    }
    float binv = (t > 0) ? 1.f / (float)t : 0.f;
    float4 m = make_float4(acc.x * binv, acc.y * binv, acc.z * binv, acc.w * binv);
    if (scale) {
      m.x = scale[c + 0] * m.x + shift[c + 0];
      m.y = scale[c + 1] * m.y + shift[c + 1];
      m.z = scale[c + 2] * m.z + shift[c + 2];
      m.w = scale[c + 3] * m.w + shift[c + 3];
    }
    As[r][c + 0] = m.x; As[r][c + 1] = m.y;
    As[r][c + 2] = m.z; As[r][c + 3] = m.w;
  }
  __syncthreads();

  // ---- GEMM: 4 rows x 4 cols per thread ----
  const int r0 = grp * 4, c0 = lane * 4;
  float acc[4][4];
  #pragma unroll
  for (int i = 0; i < 4; ++i)
    #pragma unroll
    for (int j = 0; j < 4; ++j) acc[i][j] = 0.f;

  #pragma unroll 4
  for (int kq = 0; kq < 32; ++kq) {
    float4 a0 = *reinterpret_cast<const float4*>(&As[r0 + 0][kq * 4]);
    float4 a1 = *reinterpret_cast<const float4*>(&As[r0 + 1][kq * 4]);
    float4 a2 = *reinterpret_cast<const float4*>(&As[r0 + 2][kq * 4]);
    float4 a3 = *reinterpret_cast<const float4*>(&As[r0 + 3][kq * 4]);
    float4 w0 = *reinterpret_cast<const float4*>(&W[(long)(c0 + 0) * CH + kq * 4]);
    float4 w1 = *reinterpret_cast<const float4*>(&W[(long)(c0 + 1) * CH + kq * 4]);
    float4 w2 = *reinterpret_cast<const float4*>(&W[(long)(c0 + 2) * CH + kq * 4]);
    float4 w3 = *reinterpret_cast<const float4*>(&W[(long)(c0 + 3) * CH + kq * 4]);
    const float4 aa[4] = {a0, a1, a2, a3};
    const float4 ww[4] = {w0, w1, w2, w3};
    #pragma unroll
    for (int i = 0; i < 4; ++i)
      #pragma unroll
      for (int j = 0; j < 4; ++j)
        acc[i][j] += aa[i].x * ww[j].x + aa[i].y * ww[j].y +
                     aa[i].z * ww[j].z + aa[i].w * ww[j].w;
  }

  #pragma unroll
  for (int i = 0; i < 4; ++i) {
    int ge = e0 + r0 + i;
    if (ge < NE) {
      float4 o = make_float4(acc[i][0], acc[i][1], acc[i][2], acc[i][3]);
      *reinterpret_cast<float4*>(&Eout[(long)ge * CH + c0]) = o;
    }
  }
}

// ---------------------------------------------------------------------------
// node gather: Out[i] = (1/sum hw) * sum_{e ni i} Eacc[e] + bias (32 lanes/node)
__global__ __launch_bounds__(256) void k_gather_node(const int* __restrict__ cnt_n,
    const unsigned short* __restrict__ ell_n, const float* __restrict__ hw,
    const float* __restrict__ Eacc, const float* __restrict__ bias,
    float* __restrict__ Out) {
  int gid = blockIdx.x * 256 + threadIdx.x;
  int i = gid >> 5;
  if (i >= NN) return;
  int c = (gid & 31) * 4;
  const float4 bb = *reinterpret_cast<const float4*>(&bias[c]);
  int t = cnt_n[i];
  if (t > NSTR) t = NSTR;
  const unsigned short* base = ell_n + (long)i * NSTR;
  float4 acc = make_float4(0.f, 0.f, 0.f, 0.f);
  float wsum = 0.f;
  int j = 0;
  for (; j + 4 <= t; j += 4) {
    ushort4 ee = *reinterpret_cast<const ushort4*>(base + j);
    wsum += (hw[ee.x] + hw[ee.y]) + (hw[ee.z] + hw[ee.w]);
    float4 v0 = *reinterpret_cast<const float4*>(&Eacc[(long)ee.x * CH + c]);
    float4 v1 = *reinterpret_cast<const float4*>(&Eacc[(long)ee.y * CH + c]);
    float4 v2 = *reinterpret_cast<const float4*>(&Eacc[(long)ee.z * CH + c]);
    float4 v3 = *reinterpret_cast<const float4*>(&Eacc[(long)ee.w * CH + c]);
    acc.x += (v0.x + v1.x) + (v2.x + v3.x);
    acc.y += (v0.y + v1.y) + (v2.y + v3.y);
    acc.z += (v0.z + v1.z) + (v2.z + v3.z);
    acc.w += (v0.w + v1.w) + (v2.w + v3.w);
  }
  for (; j < t; ++j) {
    int e = base[j];
    wsum += hw[e];
    float4 v = *reinterpret_cast<const float4*>(&Eacc[(long)e * CH + c]);
    acc.x += v.x; acc.y += v.y; acc.z += v.z; acc.w += v.w;
  }
  float dinv = wsum > 0.f ? 1.f / wsum : 0.f;
  float4 o;
  o.x = dinv * acc.x + bb.x; o.y = dinv * acc.y + bb.y;
  o.z = dinv * acc.z + bb.z; o.w = dinv * acc.w + bb.w;
  *reinterpret_cast<float4*>(&Out[(long)i * CH + c]) = o;
}

// ---------------------------------------------------------------------------
// streaming column stats over H (full-BW read, few atomics)
__global__ __launch_bounds__(256) void k_colstats(const float* __restrict__ H,
    float* __restrict__ colsum, float* __restrict__ colsq) {
  const int tid = threadIdx.x;
  const int cp = (tid & 63) * 2;   // channel pair
  const int rh = tid >> 6;         // row phase 0..3
  float s0 = 0, s1 = 0, q0 = 0, q1 = 0;
  for (int r = blockIdx.x * 4 + rh; r < NN; r += gridDim.x * 4) {
    float2 v = *reinterpret_cast<const float2*>(&H[(long)r * CH + cp]);
    s0 += v.x; s1 += v.y; q0 += v.x * v.x; q1 += v.y * v.y;
  }
  __shared__ float sh[256][4];
  sh[tid][0] = s0; sh[tid][1] = s1; sh[tid][2] = q0; sh[tid][3] = q1;
  __syncthreads();
  if (tid < 64) {
    float ts0 = 0, ts1 = 0, tq0 = 0, tq1 = 0;
    #pragma unroll
    for (int g = 0; g < 4; ++g) {
      ts0 += sh[tid + g * 64][0]; ts1 += sh[tid + g * 64][1];
      tq0 += sh[tid + g * 64][2]; tq1 += sh[tid + g * 64][3];
    }
    atomicAdd(&colsum[cp], ts0); atomicAdd(&colsum[cp + 1], ts1);
    atomicAdd(&colsq[cp], tq0);  atomicAdd(&colsq[cp + 1], tq1);
  }
}

// scale/shift for fused BN: a = gamma*rsqrt(var+eps), d = beta - mu*a
__global__ void k_bn_params(const float* __restrict__ colsum,
    const float* __restrict__ colsq, const float* __restrict__ gamma,
    const float* __restrict__ beta, float* __restrict__ scl,
    float* __restrict__ shf) {
  int c = threadIdx.x;
  if (c >= CH) return;
  float mu = colsum[c] * (1.f / NN);
  float var = colsq[c] * (1.f / NN) - mu * mu;
  float a = gamma[c] * rsqrtf(var + EPSV);
  scl[c] = a;
  shf[c] = beta[c] - mu * a;
}

// ---------------------------------------------------------------------------
extern "C" void kernel_launch(void* const* d_in, const int* in_sizes, int n_in,
                              void* d_out, int out_size, void* d_ws, size_t ws_size,
                              hipStream_t stream) {
  const float* x     = (const float*)d_in[0];
  const int*   hidx  = (const int*)d_in[1];   // [2][NI]
  const float* hw    = (const float*)d_in[2];
  const float* W1    = (const float*)d_in[3];
  const float* b1    = (const float*)d_in[4];
  const float* gamma = (const float*)d_in[5];
  const float* beta  = (const float*)d_in[6];
  const float* W2    = (const float*)d_in[7];
  const float* b2    = (const float*)d_in[8];
  float* out = (float*)d_out;

  const int* nidx = hidx;
  const int* eidx = hidx + NI;

  // ---- workspace layout (~15 MB); h lives in d_out ----
  char* wb = (char*)d_ws;
  int* cnt_e = (int*)wb;                                   // NE ints
  int* cnt_n = cnt_e + NE;                                 // NN ints
  unsigned short* ell_e = (unsigned short*)(cnt_n + NN);   // NE*ESTR u16
  unsigned short* ell_n = ell_e + (long)NE * ESTR;         // NN*NSTR u16
  size_t bytes = (size_t)(NE + NN) * 4 + ((size_t)NE * ESTR + (size_t)NN * NSTR) * 2;
  bytes = (bytes + 15) & ~(size_t)15;                      // 16B-align float region
  float* wf = (float*)(wb + bytes);
  float* colsum = wf;                        // 128
  float* colsq  = wf + 128;                  // 128
  float* scl    = wf + 256;                  // 128
  float* shf    = wf + 384;                  // 128
  float* Eacc   = wf + 512;                  // NE*CH (edge features post-GEMM)
  float* H      = out;                       // d_out holds h, overwritten by out

  // ---- build ELL adjacency (single pass; counts double as degrees) ----
  hipMemsetAsync(cnt_e, 0, (size_t)(NE + NN) * sizeof(int), stream);
  hipMemsetAsync(colsum, 0, 256 * sizeof(float), stream);
  k_fill_ell<<<(NI + 255) / 256, 256, 0, stream>>>(nidx, eidx, cnt_e, cnt_n,
                                                   ell_e, ell_n);

  // ---- conv1: fused edge-mean+GEMM -> Eacc, node gather -> h (d_out) ----
  k_edge_gemm<<<(NE + 31) / 32, 256, 0, stream>>>(cnt_e, ell_e, x, W1, Eacc,
                                                  nullptr, nullptr);
  k_gather_node<<<(NN * 32 + 255) / 256, 256, 0, stream>>>(cnt_n, ell_n, hw,
                                                           Eacc, b1, H);
  // ---- BatchNorm params ----
  k_colstats<<<512, 256, 0, stream>>>(H, colsum, colsq);
  k_bn_params<<<1, 128, 0, stream>>>(colsum, colsq, gamma, beta, scl, shf);

  // ---- conv2: fused edge-mean(h)+affine+GEMM -> Eacc, node gather -> out ----
  k_edge_gemm<<<(NE + 31) / 32, 256, 0, stream>>>(cnt_e, ell_e, H, W2, Eacc,
                                                  scl, shf);
  k_gather_node<<<(NN * 32 + 255) / 256, 256, 0, stream>>>(cnt_n, ell_n, hw,
                                                           Eacc, b2, out);
}

// Round 10
// 470.174 us; speedup vs baseline: 1.0441x; 1.0441x over previous
//
#include <hip/hip_runtime.h>

#define NN 50000   // nodes
#define NE 10000   // hyperedges
#define NI 800000  // incidences
#define CH 128     // channels
#define EPSV 1e-5f
#define ESTR 160   // ELL stride per edge  (deg ~ 80 +- 8.9; 160 = +9 sd)
#define NSTR 64    // ELL stride per node  (deg ~ 16 +- 4;  64 = +12 sd)
#define NPART 8    // destination partitions (== XCD count)
#define FCHUNK 2000  // incidences per block chunk (NI/FCHUNK = 400 chunks)

// ---------------------------------------------------------------------------
// destination-partitioned ELL build: partition p (= blockIdx&7 -> XCD under
// round-robin dispatch) owns e in [p*1250,..) and n in [p*6250,..). Each
// chunk of incidences is scanned by 8 blocks (one per partition); only the
// owning partition commits, so each ELL/cnt cache line is dirtied in exactly
// one XCD's L2 -> writeback ~= true dirty bytes instead of 8x.
__global__ __launch_bounds__(256) void k_fill_part(const int* __restrict__ nidx,
    const int* __restrict__ eidx, int* __restrict__ cnt_e,
    int* __restrict__ cnt_n, unsigned short* __restrict__ ell_e,
    unsigned short* __restrict__ ell_n) {
  const int part = blockIdx.x & (NPART - 1);
  const int i0 = (blockIdx.x >> 3) * FCHUNK;
  const int e_lo = part * (NE / NPART), e_hi = e_lo + NE / NPART;
  const int n_lo = part * (NN / NPART), n_hi = n_lo + NN / NPART;
  for (int i = i0 + threadIdx.x; i < i0 + FCHUNK; i += 256) {
    int n = nidx[i], e = eidx[i];
    if (e >= e_lo && e < e_hi) {
      int ce = atomicAdd(&cnt_e[e], 1);
      if (ce < ESTR) ell_e[(long)e * ESTR + ce] = (unsigned short)n;
    }
    if (n >= n_lo && n < n_hi) {
      int cn = atomicAdd(&cnt_n[n], 1);
      if (cn < NSTR) ell_n[(long)n * NSTR + cn] = (unsigned short)e;
    }
  }
}

// ---------------------------------------------------------------------------
// fused edge-mean gather + GEMM:
//   As[r][:] = (scale,shift applied) mean_{n in edge e0+r} X[n]   (LDS)
//   Eout[e][o] = sum_k As[e-e0][k] * W[o][k]
__global__ __launch_bounds__(256) void k_edge_gemm(const int* __restrict__ cnt_e,
    const unsigned short* __restrict__ ell_e, const float* __restrict__ X,
    const float* __restrict__ W, float* __restrict__ Eout,
    const float* __restrict__ scale, const float* __restrict__ shift) {
  __shared__ float As[32][132];
  const int tid = threadIdx.x;
  const int e0 = blockIdx.x * 32;
  const int lane = tid & 31, grp = tid >> 5;
  const int c = lane * 4;

  // ---- gather 32 edge means into As (8 edges in parallel, 4 rounds) ----
  for (int it = 0; it < 4; ++it) {
    int r = it * 8 + grp;
    int e = e0 + r;
    int t = 0;
    if (e < NE) { t = cnt_e[e]; if (t > ESTR) t = ESTR; }
    const unsigned short* base = ell_e + (long)e * ESTR;
    float4 acc = make_float4(0.f, 0.f, 0.f, 0.f);
    int j = 0;
    for (; j + 4 <= t; j += 4) {
      ushort4 nn = *reinterpret_cast<const ushort4*>(base + j);
      float4 v0 = *reinterpret_cast<const float4*>(&X[(long)nn.x * CH + c]);
      float4 v1 = *reinterpret_cast<const float4*>(&X[(long)nn.y * CH + c]);
      float4 v2 = *reinterpret_cast<const float4*>(&X[(long)nn.z * CH + c]);
      float4 v3 = *reinterpret_cast<const float4*>(&X[(long)nn.w * CH + c]);
      acc.x += (v0.x + v1.x) + (v2.x + v3.x);
      acc.y += (v0.y + v1.y) + (v2.y + v3.y);
      acc.z += (v0.z + v1.z) + (v2.z + v3.z);
      acc.w += (v0.w + v1.w) + (v2.w + v3.w);
    }
    for (; j < t; ++j) {
      int n = base[j];
      float4 v = *reinterpret_cast<const float4*>(&X[(long)n * CH + c]);
      acc.x += v.x; acc.y += v.y; acc.z += v.z; acc.w += v.w;
    }
    float binv = (t > 0) ? 1.f / (float)t : 0.f;
    float4 m = make_float4(acc.x * binv, acc.y * binv, acc.z * binv, acc.w * binv);
    if (scale) {
      m.x = scale[c + 0] * m.x + shift[c + 0];
      m.y = scale[c + 1] * m.y + shift[c + 1];
      m.z = scale[c + 2] * m.z + shift[c + 2];
      m.w = scale[c + 3] * m.w + shift[c + 3];
    }
    As[r][c + 0] = m.x; As[r][c + 1] = m.y;
    As[r][c + 2] = m.z; As[r][c + 3] = m.w;
  }
  __syncthreads();

  // ---- GEMM: 4 rows x 4 cols per thread ----
  const int r0 = grp * 4, c0 = lane * 4;
  float acc[4][4];
  #pragma unroll
  for (int i = 0; i < 4; ++i)
    #pragma unroll
    for (int j = 0; j < 4; ++j) acc[i][j] = 0.f;

  #pragma unroll 4
  for (int kq = 0; kq < 32; ++kq) {
    float4 a0 = *reinterpret_cast<const float4*>(&As[r0 + 0][kq * 4]);
    float4 a1 = *reinterpret_cast<const float4*>(&As[r0 + 1][kq * 4]);
    float4 a2 = *reinterpret_cast<const float4*>(&As[r0 + 2][kq * 4]);
    float4 a3 = *reinterpret_cast<const float4*>(&As[r0 + 3][kq * 4]);
    float4 w0 = *reinterpret_cast<const float4*>(&W[(long)(c0 + 0) * CH + kq * 4]);
    float4 w1 = *reinterpret_cast<const float4*>(&W[(long)(c0 + 1) * CH + kq * 4]);
    float4 w2 = *reinterpret_cast<const float4*>(&W[(long)(c0 + 2) * CH + kq * 4]);
    float4 w3 = *reinterpret_cast<const float4*>(&W[(long)(c0 + 3) * CH + kq * 4]);
    const float4 aa[4] = {a0, a1, a2, a3};
    const float4 ww[4] = {w0, w1, w2, w3};
    #pragma unroll
    for (int i = 0; i < 4; ++i)
      #pragma unroll
      for (int j = 0; j < 4; ++j)
        acc[i][j] += aa[i].x * ww[j].x + aa[i].y * ww[j].y +
                     aa[i].z * ww[j].z + aa[i].w * ww[j].w;
  }

  #pragma unroll
  for (int i = 0; i < 4; ++i) {
    int ge = e0 + r0 + i;
    if (ge < NE) {
      float4 o = make_float4(acc[i][0], acc[i][1], acc[i][2], acc[i][3]);
      *reinterpret_cast<float4*>(&Eout[(long)ge * CH + c0]) = o;
    }
  }
}

// ---------------------------------------------------------------------------
// node gather: Out[i] = (1/sum hw) * sum_{e ni i} Eacc[e] + bias (32 lanes/node)
__global__ __launch_bounds__(256) void k_gather_node(const int* __restrict__ cnt_n,
    const unsigned short* __restrict__ ell_n, const float* __restrict__ hw,
    const float* __restrict__ Eacc, const float* __restrict__ bias,
    float* __restrict__ Out) {
  int gid = blockIdx.x * 256 + threadIdx.x;
  int i = gid >> 5;
  if (i >= NN) return;
  int c = (gid & 31) * 4;
  const float4 bb = *reinterpret_cast<const float4*>(&bias[c]);
  int t = cnt_n[i];
  if (t > NSTR) t = NSTR;
  const unsigned short* base = ell_n + (long)i * NSTR;
  float4 acc = make_float4(0.f, 0.f, 0.f, 0.f);
  float wsum = 0.f;
  int j = 0;
  for (; j + 4 <= t; j += 4) {
    ushort4 ee = *reinterpret_cast<const ushort4*>(base + j);
    wsum += (hw[ee.x] + hw[ee.y]) + (hw[ee.z] + hw[ee.w]);
    float4 v0 = *reinterpret_cast<const float4*>(&Eacc[(long)ee.x * CH + c]);
    float4 v1 = *reinterpret_cast<const float4*>(&Eacc[(long)ee.y * CH + c]);
    float4 v2 = *reinterpret_cast<const float4*>(&Eacc[(long)ee.z * CH + c]);
    float4 v3 = *reinterpret_cast<const float4*>(&Eacc[(long)ee.w * CH + c]);
    acc.x += (v0.x + v1.x) + (v2.x + v3.x);
    acc.y += (v0.y + v1.y) + (v2.y + v3.y);
    acc.z += (v0.z + v1.z) + (v2.z + v3.z);
    acc.w += (v0.w + v1.w) + (v2.w + v3.w);
  }
  for (; j < t; ++j) {
    int e = base[j];
    wsum += hw[e];
    float4 v = *reinterpret_cast<const float4*>(&Eacc[(long)e * CH + c]);
    acc.x += v.x; acc.y += v.y; acc.z += v.z; acc.w += v.w;
  }
  float dinv = wsum > 0.f ? 1.f / wsum : 0.f;
  float4 o;
  o.x = dinv * acc.x + bb.x; o.y = dinv * acc.y + bb.y;
  o.z = dinv * acc.z + bb.z; o.w = dinv * acc.w + bb.w;
  *reinterpret_cast<float4*>(&Out[(long)i * CH + c]) = o;
}

// ---------------------------------------------------------------------------
// streaming column stats over H (full-BW read, few atomics)
__global__ __launch_bounds__(256) void k_colstats(const float* __restrict__ H,
    float* __restrict__ colsum, float* __restrict__ colsq) {
  const int tid = threadIdx.x;
  const int cp = (tid & 63) * 2;   // channel pair
  const int rh = tid >> 6;         // row phase 0..3
  float s0 = 0, s1 = 0, q0 = 0, q1 = 0;
  for (int r = blockIdx.x * 4 + rh; r < NN; r += gridDim.x * 4) {
    float2 v = *reinterpret_cast<const float2*>(&H[(long)r * CH + cp]);
    s0 += v.x; s1 += v.y; q0 += v.x * v.x; q1 += v.y * v.y;
  }
  __shared__ float sh[256][4];
  sh[tid][0] = s0; sh[tid][1] = s1; sh[tid][2] = q0; sh[tid][3] = q1;
  __syncthreads();
  if (tid < 64) {
    float ts0 = 0, ts1 = 0, tq0 = 0, tq1 = 0;
    #pragma unroll
    for (int g = 0; g < 4; ++g) {
      ts0 += sh[tid + g * 64][0]; ts1 += sh[tid + g * 64][1];
      tq0 += sh[tid + g * 64][2]; tq1 += sh[tid + g * 64][3];
    }
    atomicAdd(&colsum[cp], ts0); atomicAdd(&colsum[cp + 1], ts1);
    atomicAdd(&colsq[cp], tq0);  atomicAdd(&colsq[cp + 1], tq1);
  }
}

// scale/shift for fused BN: a = gamma*rsqrt(var+eps), d = beta - mu*a
__global__ void k_bn_params(const float* __restrict__ colsum,
    const float* __restrict__ colsq, const float* __restrict__ gamma,
    const float* __restrict__ beta, float* __restrict__ scl,
    float* __restrict__ shf) {
  int c = threadIdx.x;
  if (c >= CH) return;
  float mu = colsum[c] * (1.f / NN);
  float var = colsq[c] * (1.f / NN) - mu * mu;
  float a = gamma[c] * rsqrtf(var + EPSV);
  scl[c] = a;
  shf[c] = beta[c] - mu * a;
}

// ---------------------------------------------------------------------------
extern "C" void kernel_launch(void* const* d_in, const int* in_sizes, int n_in,
                              void* d_out, int out_size, void* d_ws, size_t ws_size,
                              hipStream_t stream) {
  const float* x     = (const float*)d_in[0];
  const int*   hidx  = (const int*)d_in[1];   // [2][NI]
  const float* hw    = (const float*)d_in[2];
  const float* W1    = (const float*)d_in[3];
  const float* b1    = (const float*)d_in[4];
  const float* gamma = (const float*)d_in[5];
  const float* beta  = (const float*)d_in[6];
  const float* W2    = (const float*)d_in[7];
  const float* b2    = (const float*)d_in[8];
  float* out = (float*)d_out;

  const int* nidx = hidx;
  const int* eidx = hidx + NI;

  // ---- workspace layout (~15 MB); h lives in d_out ----
  char* wb = (char*)d_ws;
  int* cnt_e = (int*)wb;                                   // NE ints
  int* cnt_n = cnt_e + NE;                                 // NN ints
  unsigned short* ell_e = (unsigned short*)(cnt_n + NN);   // NE*ESTR u16
  unsigned short* ell_n = ell_e + (long)NE * ESTR;         // NN*NSTR u16
  size_t bytes = (size_t)(NE + NN) * 4 + ((size_t)NE * ESTR + (size_t)NN * NSTR) * 2;
  bytes = (bytes + 15) & ~(size_t)15;                      // 16B-align float region
  float* wf = (float*)(wb + bytes);
  float* colsum = wf;                        // 128
  float* colsq  = wf + 128;                  // 128
  float* scl    = wf + 256;                  // 128
  float* shf    = wf + 384;                  // 128
  float* Eacc   = wf + 512;                  // NE*CH (edge features post-GEMM)
  float* H      = out;                       // d_out holds h, overwritten by out

  // ---- build ELL adjacency (destination-partitioned single pass) ----
  hipMemsetAsync(cnt_e, 0, (size_t)(NE + NN) * sizeof(int), stream);
  hipMemsetAsync(colsum, 0, 256 * sizeof(float), stream);
  k_fill_part<<<(NI / FCHUNK) * NPART, 256, 0, stream>>>(nidx, eidx, cnt_e, cnt_n,
                                                         ell_e, ell_n);

  // ---- conv1: fused edge-mean+GEMM -> Eacc, node gather -> h (d_out) ----
  k_edge_gemm<<<(NE + 31) / 32, 256, 0, stream>>>(cnt_e, ell_e, x, W1, Eacc,
                                                  nullptr, nullptr);
  k_gather_node<<<(NN * 32 + 255) / 256, 256, 0, stream>>>(cnt_n, ell_n, hw,
                                                           Eacc, b1, H);
  // ---- BatchNorm params ----
  k_colstats<<<512, 256, 0, stream>>>(H, colsum, colsq);
  k_bn_params<<<1, 128, 0, stream>>>(colsum, colsq, gamma, beta, scl, shf);

  // ---- conv2: fused edge-mean(h)+affine+GEMM -> Eacc, node gather -> out ----
  k_edge_gemm<<<(NE + 31) / 32, 256, 0, stream>>>(cnt_e, ell_e, H, W2, Eacc,
                                                  scl, shf);
  k_gather_node<<<(NN * 32 + 255) / 256, 256, 0, stream>>>(cnt_n, ell_n, hw,
                                                           Eacc, b2, out);
}